// Round 1
// baseline (241.413 us; speedup 1.0000x reference)
//
#include <hip/hip_runtime.h>

#define T_SEQ   4096
#define D_MODEL 1024
#define NH      16
#define HD      64
#define E3      3072
#define ATT_SCALE 0.125f

using u32x4  = __attribute__((ext_vector_type(4))) unsigned int;
using u16x4  = __attribute__((ext_vector_type(4))) unsigned short;
using f32x4  = __attribute__((ext_vector_type(4))) float;
using bf16x8 = __attribute__((ext_vector_type(8))) __bf16;

__device__ __forceinline__ unsigned short f2bf(float f){
  unsigned int u = __builtin_bit_cast(unsigned int, f);
  u += 0x7fffu + ((u >> 16) & 1u);          // RNE
  return (unsigned short)(u >> 16);
}

__device__ __forceinline__ void gload_lds16(const void* g, void* l){
  __builtin_amdgcn_global_load_lds((const __attribute__((address_space(1))) void*)g,
                                   (__attribute__((address_space(3))) void*)l, 16, 0, 0);
}

// ---------------- fp32 -> bf16 convert ----------------
__global__ __launch_bounds__(256) void cvt_f32_bf16(const float4* __restrict__ in,
                                                    u16x4* __restrict__ out, int n4){
  int i = blockIdx.x * 256 + threadIdx.x;
  if(i < n4){
    float4 v = in[i];
    u16x4 o = { f2bf(v.x), f2bf(v.y), f2bf(v.z), f2bf(v.w) };
    out[i] = o;
  }
}

// ---------------- C = A * B^T  (A[M,K], B[N,K] row-major, bf16 in, fp32 acc) --------
// 128x128 tile, BK=32, 4 waves (2x2 of 64x64), 4x4 16x16 frags per wave. m97 structure.
template<int OUT_BF16>
__global__ __launch_bounds__(256) void gemm_bt(const unsigned short* __restrict__ A,
                                               const unsigned short* __restrict__ B,
                                               void* __restrict__ Cv,
                                               int M, int N, int K){
  __shared__ unsigned short As[128*32];
  __shared__ unsigned short Bs[128*32];
  const int t    = threadIdx.x;
  const int lane = t & 63;
  const int w    = t >> 6;
  const int brow = blockIdx.y * 128;
  const int bcol = blockIdx.x * 128;
  const int wrow = (w >> 1) * 64;
  const int wcol = (w & 1) * 64;
  const int cc = lane & 15;
  const int gg = lane >> 4;

  f32x4 acc[4][4];
  #pragma unroll
  for(int m=0;m<4;++m)
    #pragma unroll
    for(int n=0;n<4;++n)
      acc[m][n] = (f32x4){0.f,0.f,0.f,0.f};

  const int srow = t >> 2;          // 0..63
  const int sk   = (t & 3) * 8;
  const long aBase = (long)(brow + srow) * K;
  const long bBase = (long)(bcol + srow) * K;

  for(int k0 = 0; k0 < K; k0 += 32){
    __syncthreads();
    gload_lds16(A + aBase + k0 + sk,               As + t*8);
    gload_lds16(A + aBase + 64*(long)K + k0 + sk,  As + 2048 + t*8);
    gload_lds16(B + bBase + k0 + sk,               Bs + t*8);
    gload_lds16(B + bBase + 64*(long)K + k0 + sk,  Bs + 2048 + t*8);
    __syncthreads();

    bf16x8 af[4], bfr[4];
    #pragma unroll
    for(int m=0;m<4;++m)
      af[m]  = *(const bf16x8*)((const char*)As + (wrow + m*16 + cc)*64 + gg*16);
    #pragma unroll
    for(int n=0;n<4;++n)
      bfr[n] = *(const bf16x8*)((const char*)Bs + (wcol + n*16 + cc)*64 + gg*16);
    #pragma unroll
    for(int m=0;m<4;++m)
      #pragma unroll
      for(int n=0;n<4;++n)
        acc[m][n] = __builtin_amdgcn_mfma_f32_16x16x32_bf16(af[m], bfr[n], acc[m][n], 0, 0, 0);
  }

  #pragma unroll
  for(int m=0;m<4;++m){
    #pragma unroll
    for(int n=0;n<4;++n){
      const int row0 = brow + wrow + m*16 + gg*4;
      const int col  = bcol + wcol + n*16 + cc;
      #pragma unroll
      for(int r=0;r<4;++r){
        if constexpr (OUT_BF16 != 0){
          ((unsigned short*)Cv)[(long)(row0 + r)*N + col] = f2bf(acc[m][n][r]);
        } else {
          ((float*)Cv)[(long)(row0 + r)*N + col] = acc[m][n][r];
        }
      }
    }
  }
}

// ---------------- fused causal attention ----------------
// block = (head h, 64 q-rows). 4 waves x 16 q-rows. KV blocks of 32 keys.
// clamp(+-10) before mask => exp without max tracking; masked entries exact 0.
__global__ __launch_bounds__(256) void attn_fused(const unsigned short* __restrict__ qkv,
                                                  unsigned short* __restrict__ aout){
  __shared__ unsigned short Ks[32*64];      // K tile, rows 128B, chunk^=(row&7) swizzle
  __shared__ unsigned short VTs[64*32];     // V^T tile, rows 64B, chunk^=f(row) swizzle
  __shared__ unsigned short Ps[4][16*32];   // per-wave P tile, rows 64B

  const int t    = threadIdx.x;
  const int lane = t & 63;
  const int w    = t >> 6;
  const int h    = blockIdx.y;
  const int qb   = 63 - (int)blockIdx.x;    // heavy blocks first
  const int q0   = qb*64 + w*16;
  const int cc = lane & 15;
  const int gg = lane >> 4;

  bf16x8 aq[2];
  {
    const long qrow = q0 + cc;
    aq[0] = *(const bf16x8*)(qkv + qrow*E3 + h*HD + 0  + gg*8);
    aq[1] = *(const bf16x8*)(qkv + qrow*E3 + h*HD + 32 + gg*8);
  }

  f32x4 acc[4];
  #pragma unroll
  for(int vt=0;vt<4;++vt) acc[vt] = (f32x4){0.f,0.f,0.f,0.f};
  float rs[4] = {0.f,0.f,0.f,0.f};

  const int skey = t >> 3;        // 0..31  (K staging)
  const int schn = t & 7;         // 0..7
  const int vdk  = 2*(t & 31);    // V staging: dk pair
  const int vk0  = 4*(t >> 5);    // V staging: 4 keys

  const int kbmax = 2*qb + 1;
  for(int kb = 0; kb <= kbmax; ++kb){
    __syncthreads();
    { // stage K[32 x 64], swizzled
      u32x4 kvec = *(const u32x4*)(qkv + (long)(kb*32 + skey)*E3 + D_MODEL + h*HD + schn*8);
      *(u32x4*)((char*)Ks + skey*128 + ((schn ^ (skey & 7)) << 4)) = kvec;
    }
    { // stage V^T[64 x 32] via register transpose of 4x2 micro-blocks
      const unsigned short* vb = qkv + 2*D_MODEL + h*HD + vdk;
      unsigned int u0 = __builtin_bit_cast(unsigned int, *(const float*)(vb + (long)(kb*32 + vk0 + 0)*E3));
      unsigned int u1 = __builtin_bit_cast(unsigned int, *(const float*)(vb + (long)(kb*32 + vk0 + 1)*E3));
      unsigned int u2 = __builtin_bit_cast(unsigned int, *(const float*)(vb + (long)(kb*32 + vk0 + 2)*E3));
      unsigned int u3 = __builtin_bit_cast(unsigned int, *(const float*)(vb + (long)(kb*32 + vk0 + 3)*E3));
      u16x4 lo = { (unsigned short)u0, (unsigned short)u1, (unsigned short)u2, (unsigned short)u3 };
      u16x4 hi = { (unsigned short)(u0>>16), (unsigned short)(u1>>16),
                   (unsigned short)(u2>>16), (unsigned short)(u3>>16) };
      const int bin = vk0*2;                                  // 0..56, mult of 8
      const int f0 = (vdk & 3) ^ ((vdk >> 2) & 3);
      const int f1 = ((vdk+1) & 3) ^ (((vdk+1) >> 2) & 3);
      *(u16x4*)((char*)VTs + vdk*64     + (bin & 8) + (((bin>>4) ^ f0) << 4)) = lo;
      *(u16x4*)((char*)VTs + (vdk+1)*64 + (bin & 8) + (((bin>>4) ^ f1) << 4)) = hi;
    }
    __syncthreads();

    // S = Q K^T for two 16-key subtiles; clamp, mask, exp; P -> LDS (wave-private)
    #pragma unroll
    for(int kt=0; kt<2; ++kt){
      const int krow = kt*16 + cc;
      const char* kbase = (const char*)Ks + krow*128;
      bf16x8 bk0 = *(const bf16x8*)(kbase + (((0 + gg) ^ (krow & 7)) << 4));
      bf16x8 bk1 = *(const bf16x8*)(kbase + (((4 + gg) ^ (krow & 7)) << 4));
      f32x4 s = __builtin_amdgcn_mfma_f32_16x16x32_bf16(aq[0], bk0, (f32x4){0.f,0.f,0.f,0.f}, 0,0,0);
      s = __builtin_amdgcn_mfma_f32_16x16x32_bf16(aq[1], bk1, s, 0,0,0);
      const int key = kb*32 + kt*16 + cc;
      #pragma unroll
      for(int r=0;r<4;++r){
        float sv = s[r] * ATT_SCALE;
        sv = fminf(fmaxf(sv, -10.f), 10.f);
        const int qrow = q0 + gg*4 + r;
        float p = (key <= qrow) ? __expf(sv) : 0.f;
        rs[r] += p;
        const int prow = gg*4 + r;
        const int fp   = r ^ gg;                  // f(prow)
        const int bin  = (kt*16 + cc)*2;
        *(unsigned short*)((char*)&Ps[w][0] + prow*64 + (bin & 15) + (((bin>>4) ^ fp) << 4)) = f2bf(p);
      }
    }

    { // PV: O += P[16x32] * V[32x64]
      const int fc = (cc & 3) ^ ((cc >> 2) & 3);
      bf16x8 ap = *(const bf16x8*)((const char*)&Ps[w][0] + cc*64 + ((gg ^ fc) << 4));
      #pragma unroll
      for(int vt=0; vt<4; ++vt){
        const int vrow = vt*16 + cc;
        const int fv = (vrow & 3) ^ ((vrow >> 2) & 3);
        bf16x8 bv = *(const bf16x8*)((const char*)VTs + vrow*64 + ((gg ^ fv) << 4));
        acc[vt] = __builtin_amdgcn_mfma_f32_16x16x32_bf16(ap, bv, acc[vt], 0,0,0);
      }
    }
  }

  // rowsum reduce across the 16 lanes of each group (keys live on cc)
  #pragma unroll
  for(int r=0;r<4;++r){
    float v = rs[r];
    v += __shfl_xor(v, 1);
    v += __shfl_xor(v, 2);
    v += __shfl_xor(v, 4);
    v += __shfl_xor(v, 8);
    rs[r] = v;
  }

  #pragma unroll
  for(int vt=0; vt<4; ++vt){
    #pragma unroll
    for(int r=0;r<4;++r){
      const int row = q0 + gg*4 + r;
      const int col = h*HD + vt*16 + cc;
      aout[(long)row*D_MODEL + col] = f2bf(acc[vt][r] / rs[r]);
    }
  }
}

extern "C" void kernel_launch(void* const* d_in, const int* in_sizes, int n_in,
                              void* d_out, int out_size, void* d_ws, size_t ws_size,
                              hipStream_t stream){
  (void)in_sizes; (void)n_in; (void)out_size; (void)ws_size;
  const float* x    = (const float*)d_in[0];
  const float* wqkv = (const float*)d_in[1];
  const float* wout = (const float*)d_in[2];
  char* ws = (char*)d_ws;
  unsigned short* xb    = (unsigned short*)(ws);                 //  8 MB
  unsigned short* wqkvb = (unsigned short*)(ws + (8u  << 20));   //  6 MB
  unsigned short* woutb = (unsigned short*)(ws + (14u << 20));   //  2 MB
  unsigned short* qkvb  = (unsigned short*)(ws + (16u << 20));   // 24 MB
  unsigned short* attnb = (unsigned short*)(ws + (40u << 20));   //  8 MB
  float* out = (float*)d_out;

  cvt_f32_bf16<<<(T_SEQ*D_MODEL/4 + 255)/256, 256, 0, stream>>>((const float4*)x,    (u16x4*)xb,    T_SEQ*D_MODEL/4);
  cvt_f32_bf16<<<(E3*D_MODEL/4   + 255)/256, 256, 0, stream>>>((const float4*)wqkv, (u16x4*)wqkvb, E3*D_MODEL/4);
  cvt_f32_bf16<<<(D_MODEL*D_MODEL/4 + 255)/256, 256, 0, stream>>>((const float4*)wout, (u16x4*)woutb, D_MODEL*D_MODEL/4);

  dim3 g1(E3/128, T_SEQ/128);
  gemm_bt<1><<<g1, 256, 0, stream>>>(xb, wqkvb, qkvb, T_SEQ, E3, D_MODEL);

  dim3 g2(64, NH);
  attn_fused<<<g2, 256, 0, stream>>>(qkvb, attnb);

  dim3 g3(D_MODEL/128, T_SEQ/128);
  gemm_bt<0><<<g3, 256, 0, stream>>>(attnb, woutb, out, T_SEQ, D_MODEL, D_MODEL);
}

// Round 2
// 176.035 us; speedup vs baseline: 1.3714x; 1.3714x over previous
//
#include <hip/hip_runtime.h>

#define T_SEQ   4096
#define D_MODEL 1024
#define NH      16
#define HD      64
#define E3      3072
#define ATT_SCALE 0.125f

using u32x4  = __attribute__((ext_vector_type(4))) unsigned int;
using u16x4  = __attribute__((ext_vector_type(4))) unsigned short;
using u16x8  = __attribute__((ext_vector_type(8))) unsigned short;
using f32x4  = __attribute__((ext_vector_type(4))) float;
using bf16x8 = __attribute__((ext_vector_type(8))) __bf16;

__device__ __forceinline__ unsigned short f2bf(float f){
  unsigned int u = __builtin_bit_cast(unsigned int, f);
  u += 0x7fffu + ((u >> 16) & 1u);          // RNE
  return (unsigned short)(u >> 16);
}

__device__ __forceinline__ void gload_lds16(const void* g, void* l){
  __builtin_amdgcn_global_load_lds((const __attribute__((address_space(1))) void*)g,
                                   (__attribute__((address_space(3))) void*)l, 16, 0, 0);
}

// ---------------- fp32 -> bf16 convert ----------------
__global__ __launch_bounds__(256) void cvt_f32_bf16(const float4* __restrict__ in,
                                                    u16x4* __restrict__ out, int n4){
  int i = blockIdx.x * 256 + threadIdx.x;
  if(i < n4){
    float4 v = in[i];
    u16x4 o = { f2bf(v.x), f2bf(v.y), f2bf(v.z), f2bf(v.w) };
    out[i] = o;
  }
}

// ---------------- C = A * B^T  (A[M,K], B[N,K] row-major, bf16 in, fp32 acc) --------
template<int OUT_BF16>
__global__ __launch_bounds__(256) void gemm_bt(const unsigned short* __restrict__ A,
                                               const unsigned short* __restrict__ B,
                                               void* __restrict__ Cv,
                                               int M, int N, int K){
  __shared__ unsigned short As[128*32];
  __shared__ unsigned short Bs[128*32];
  const int t    = threadIdx.x;
  const int lane = t & 63;
  const int w    = t >> 6;
  const int brow = blockIdx.y * 128;
  const int bcol = blockIdx.x * 128;
  const int wrow = (w >> 1) * 64;
  const int wcol = (w & 1) * 64;
  const int cc = lane & 15;
  const int gg = lane >> 4;

  f32x4 acc[4][4];
  #pragma unroll
  for(int m=0;m<4;++m)
    #pragma unroll
    for(int n=0;n<4;++n)
      acc[m][n] = (f32x4){0.f,0.f,0.f,0.f};

  const int srow = t >> 2;
  const int sk   = (t & 3) * 8;
  const long aBase = (long)(brow + srow) * K;
  const long bBase = (long)(bcol + srow) * K;

  for(int k0 = 0; k0 < K; k0 += 32){
    __syncthreads();
    gload_lds16(A + aBase + k0 + sk,               As + t*8);
    gload_lds16(A + aBase + 64*(long)K + k0 + sk,  As + 2048 + t*8);
    gload_lds16(B + bBase + k0 + sk,               Bs + t*8);
    gload_lds16(B + bBase + 64*(long)K + k0 + sk,  Bs + 2048 + t*8);
    __syncthreads();

    bf16x8 af[4], bfr[4];
    #pragma unroll
    for(int m=0;m<4;++m)
      af[m]  = *(const bf16x8*)((const char*)As + (wrow + m*16 + cc)*64 + gg*16);
    #pragma unroll
    for(int n=0;n<4;++n)
      bfr[n] = *(const bf16x8*)((const char*)Bs + (wcol + n*16 + cc)*64 + gg*16);
    #pragma unroll
    for(int m=0;m<4;++m)
      #pragma unroll
      for(int n=0;n<4;++n)
        acc[m][n] = __builtin_amdgcn_mfma_f32_16x16x32_bf16(af[m], bfr[n], acc[m][n], 0, 0, 0);
  }

  #pragma unroll
  for(int m=0;m<4;++m){
    #pragma unroll
    for(int n=0;n<4;++n){
      const int row0 = brow + wrow + m*16 + gg*4;
      const int col  = bcol + wcol + n*16 + cc;
      #pragma unroll
      for(int r=0;r<4;++r){
        if constexpr (OUT_BF16 != 0){
          ((unsigned short*)Cv)[(long)(row0 + r)*N + col] = f2bf(acc[m][n][r]);
        } else {
          ((float*)Cv)[(long)(row0 + r)*N + col] = acc[m][n][r];
        }
      }
    }
  }
}

// ---------------- fused causal attention v2 ----------------
// block = (head hd, 128 q-rows), 4 waves x 32 q-rows. KVBLK=64, double-buffered.
// Swapped QK^T (S^T = K·Q^T) so each lane holds 4 contiguous keys -> b64 P writes.
// Swizzles: K chunk^=(row&7); V^T chunk^=((d>>1)&7); P chunk^=(row&7).
__global__ __launch_bounds__(256) void attn_fused(const unsigned short* __restrict__ qkv,
                                                  unsigned short* __restrict__ aout){
  __shared__ unsigned short Ks[2][64*64];
  __shared__ unsigned short VTs[2][64*64];
  __shared__ unsigned short Ps[4][32*64];

  const int t    = threadIdx.x;
  const int lane = t & 63;
  const int w    = t >> 6;
  const int cc   = lane & 15;
  const int gg   = lane >> 4;

  const int bid  = blockIdx.x;
  const int qb   = 31 - (bid >> 4);       // heavy (long-KV) blocks first, all heads
  const int hd   = bid & 15;
  const int q0w  = qb*128 + w*32;
  const int nkv  = 2*qb + 2;

  // Q fragments (B-operand of swapped QK): row = q0w+qt*16+cc, dk = 32*hh + 8*gg
  bf16x8 bq[2][2];
  #pragma unroll
  for(int qt=0;qt<2;++qt)
    #pragma unroll
    for(int hh=0;hh<2;++hh)
      bq[qt][hh] = *(const bf16x8*)(qkv + (long)(q0w+qt*16+cc)*E3 + hd*HD + hh*32 + gg*8);

  f32x4 acc[2][4];
  #pragma unroll
  for(int qt=0;qt<2;++qt)
    #pragma unroll
    for(int vt=0;vt<4;++vt)
      acc[qt][vt] = (f32x4){0.f,0.f,0.f,0.f};
  float rs[2] = {0.f, 0.f};

  const int dp = t & 31;                  // V staging: dk pair
  const int ko = t >> 5;                  // V staging: key octet

  // K stage: LDS linear dest, pre-swizzled global source (content chunk c^=(row&7))
  #define STAGE_K(kb_, buf_) do{                                                   \
    _Pragma("unroll")                                                              \
    for(int pass=0; pass<2; ++pass){                                               \
      const int s   = pass*4096 + t*16;                                            \
      const int row = s >> 7;                                                      \
      const int cp  = ((s>>4)&7) ^ (row&7);                                        \
      gload_lds16(qkv + (long)((kb_)*64+row)*E3 + D_MODEL + hd*HD + cp*8,          \
                  (char*)Ks[buf_] + s);                                            \
    } }while(0)

  #define VLOAD(kb_, vr_) do{                                                      \
    _Pragma("unroll")                                                              \
    for(int j=0;j<8;++j)                                                           \
      vr_[j] = *(const unsigned int*)(qkv + (long)((kb_)*64 + ko*8 + j)*E3         \
                                      + 2*D_MODEL + hd*HD + 2*dp);                 \
    }while(0)

  #define VWRITE(buf_, vr_) do{                                                    \
    u16x8 lo_, hi_;                                                                \
    _Pragma("unroll")                                                              \
    for(int j=0;j<8;++j){ lo_[j]=(unsigned short)vr_[j];                           \
                          hi_[j]=(unsigned short)(vr_[j]>>16); }                   \
    const int c0_ = ko ^ (dp&7);                                                   \
    *(u16x8*)((char*)VTs[buf_] + (2*dp  )*128 + c0_*16) = lo_;                     \
    *(u16x8*)((char*)VTs[buf_] + (2*dp+1)*128 + c0_*16) = hi_;                     \
    }while(0)

  unsigned int vr[8];
  STAGE_K(0, 0);
  VLOAD(0, vr);
  VWRITE(0, vr);
  __syncthreads();

  for(int kb=0; kb<nkv; ++kb){
    const int cur = kb & 1;
    const bool pf = (kb+1 < nkv);
    if(pf){ STAGE_K(kb+1, cur^1); VLOAD(kb+1, vr); }

    // ---- S^T = K·Q^T, clamp, mask, exp, pack -> Ps ----
    #pragma unroll
    for(int kt=0; kt<4; ++kt){
      const char* kro = (const char*)Ks[cur] + (16*kt+cc)*128;
      bf16x8 a0 = *(const bf16x8*)(kro + (((gg  ) ^ (cc&7)) << 4));
      bf16x8 a1 = *(const bf16x8*)(kro + (((gg+4) ^ (cc&7)) << 4));
      #pragma unroll
      for(int qt=0; qt<2; ++qt){
        f32x4 s = __builtin_amdgcn_mfma_f32_16x16x32_bf16(a0, bq[qt][0], (f32x4){0.f,0.f,0.f,0.f}, 0,0,0);
        s = __builtin_amdgcn_mfma_f32_16x16x32_bf16(a1, bq[qt][1], s, 0,0,0);
        const int qrow = q0w + qt*16 + cc;
        u16x4 pk;
        #pragma unroll
        for(int r=0;r<4;++r){
          const int key = kb*64 + kt*16 + gg*4 + r;
          float sv = s[r] * ATT_SCALE;
          sv = fminf(fmaxf(sv, -10.f), 10.f);
          float p = (key <= qrow) ? __expf(sv) : 0.f;
          rs[qt] += p;
          pk[r] = f2bf(p);
        }
        *(u16x4*)((char*)Ps[w] + (qt*16+cc)*128
                  + (((2*kt + (gg>>1)) ^ (cc&7)) << 4) + (gg&1)*8) = pk;
      }
    }

    // ---- O += P · V  (A = P rows, B = V^T rows) ----
    #pragma unroll
    for(int hh=0; hh<2; ++hh){
      bf16x8 pa0 = *(const bf16x8*)((const char*)Ps[w] + (cc   )*128 + (((gg+4*hh) ^ (cc&7)) << 4));
      bf16x8 pa1 = *(const bf16x8*)((const char*)Ps[w] + (16+cc)*128 + (((gg+4*hh) ^ (cc&7)) << 4));
      #pragma unroll
      for(int vt=0; vt<4; ++vt){
        bf16x8 bv = *(const bf16x8*)((const char*)VTs[cur] + (vt*16+cc)*128
                                     + (((gg+4*hh) ^ ((cc>>1)&7)) << 4));
        acc[0][vt] = __builtin_amdgcn_mfma_f32_16x16x32_bf16(pa0, bv, acc[0][vt], 0,0,0);
        acc[1][vt] = __builtin_amdgcn_mfma_f32_16x16x32_bf16(pa1, bv, acc[1][vt], 0,0,0);
      }
    }

    if(pf) VWRITE(cur^1, vr);
    __syncthreads();
  }

  // rowsum: lane-local over its key-residues; reduce over gg (lane bits 4,5)
  #pragma unroll
  for(int qt=0;qt<2;++qt){
    float v = rs[qt];
    v += __shfl_xor(v, 16);
    v += __shfl_xor(v, 32);
    rs[qt] = v;
  }

  #pragma unroll
  for(int qt=0;qt<2;++qt){
    #pragma unroll
    for(int r=0;r<4;++r){
      const float rsv = __shfl(rs[qt], gg*4 + r);   // lane gg*4+r holds q = qt*16+(gg*4+r)
      const float inv = 1.0f / rsv;
      const int row = q0w + qt*16 + gg*4 + r;
      #pragma unroll
      for(int vt=0;vt<4;++vt)
        aout[(long)row*D_MODEL + hd*HD + vt*16 + cc] = f2bf(acc[qt][vt][r] * inv);
    }
  }
  #undef STAGE_K
  #undef VLOAD
  #undef VWRITE
}

extern "C" void kernel_launch(void* const* d_in, const int* in_sizes, int n_in,
                              void* d_out, int out_size, void* d_ws, size_t ws_size,
                              hipStream_t stream){
  (void)in_sizes; (void)n_in; (void)out_size; (void)ws_size;
  const float* x    = (const float*)d_in[0];
  const float* wqkv = (const float*)d_in[1];
  const float* wout = (const float*)d_in[2];
  char* ws = (char*)d_ws;
  unsigned short* xb    = (unsigned short*)(ws);                 //  8 MB
  unsigned short* wqkvb = (unsigned short*)(ws + (8u  << 20));   //  6 MB
  unsigned short* woutb = (unsigned short*)(ws + (14u << 20));   //  2 MB
  unsigned short* qkvb  = (unsigned short*)(ws + (16u << 20));   // 24 MB
  unsigned short* attnb = (unsigned short*)(ws + (40u << 20));   //  8 MB
  float* out = (float*)d_out;

  cvt_f32_bf16<<<(T_SEQ*D_MODEL/4 + 255)/256, 256, 0, stream>>>((const float4*)x,    (u16x4*)xb,    T_SEQ*D_MODEL/4);
  cvt_f32_bf16<<<(E3*D_MODEL/4   + 255)/256, 256, 0, stream>>>((const float4*)wqkv, (u16x4*)wqkvb, E3*D_MODEL/4);
  cvt_f32_bf16<<<(D_MODEL*D_MODEL/4 + 255)/256, 256, 0, stream>>>((const float4*)wout, (u16x4*)woutb, D_MODEL*D_MODEL/4);

  dim3 g1(E3/128, T_SEQ/128);
  gemm_bt<1><<<g1, 256, 0, stream>>>(xb, wqkvb, qkvb, T_SEQ, E3, D_MODEL);

  attn_fused<<<dim3(32*NH), 256, 0, stream>>>(qkvb, attnb);

  dim3 g3(D_MODEL/128, T_SEQ/128);
  gemm_bt<0><<<g3, 256, 0, stream>>>(attnb, woutb, out, T_SEQ, D_MODEL, D_MODEL);
}

// Round 3
// 166.075 us; speedup vs baseline: 1.4536x; 1.0600x over previous
//
#include <hip/hip_runtime.h>

#define T_SEQ   4096
#define D_MODEL 1024
#define NH      16
#define HD      64
#define E3      3072

using u32x2  = __attribute__((ext_vector_type(2))) unsigned int;
using u32x4  = __attribute__((ext_vector_type(4))) unsigned int;
using u16x4  = __attribute__((ext_vector_type(4))) unsigned short;
using f32x4  = __attribute__((ext_vector_type(4))) float;
using bf16x8 = __attribute__((ext_vector_type(8))) __bf16;

__device__ __forceinline__ unsigned short f2bf(float f){
  unsigned int u = __builtin_bit_cast(unsigned int, f);
  u += 0x7fffu + ((u >> 16) & 1u);          // RNE
  return (unsigned short)(u >> 16);
}

__device__ __forceinline__ void gload_lds16(const void* g, void* l){
  __builtin_amdgcn_global_load_lds((const __attribute__((address_space(1))) void*)g,
                                   (__attribute__((address_space(3))) void*)l, 16, 0, 0);
}

// ---------------- fp32 -> bf16 convert ----------------
__global__ __launch_bounds__(256) void cvt_f32_bf16(const float4* __restrict__ in,
                                                    u16x4* __restrict__ out, int n4){
  int i = blockIdx.x * 256 + threadIdx.x;
  if(i < n4){
    float4 v = in[i];
    u16x4 o = { f2bf(v.x), f2bf(v.y), f2bf(v.z), f2bf(v.w) };
    out[i] = o;
  }
}

// ---------------- C = A * B^T  (A[M,K], B[N,K] row-major, bf16 in, fp32 acc) --------
// QSCALE: multiply cols < D_MODEL by 0.125 (folds attention scale into Q, exact pow2)
template<int OUT_BF16, int QSCALE>
__global__ __launch_bounds__(256) void gemm_bt(const unsigned short* __restrict__ A,
                                               const unsigned short* __restrict__ B,
                                               void* __restrict__ Cv,
                                               int M, int N, int K){
  __shared__ unsigned short As[128*32];
  __shared__ unsigned short Bs[128*32];
  const int t    = threadIdx.x;
  const int lane = t & 63;
  const int w    = t >> 6;
  const int brow = blockIdx.y * 128;
  const int bcol = blockIdx.x * 128;
  const int wrow = (w >> 1) * 64;
  const int wcol = (w & 1) * 64;
  const int cc = lane & 15;
  const int gg = lane >> 4;

  f32x4 acc[4][4];
  #pragma unroll
  for(int m=0;m<4;++m)
    #pragma unroll
    for(int n=0;n<4;++n)
      acc[m][n] = (f32x4){0.f,0.f,0.f,0.f};

  const int srow = t >> 2;
  const int sk   = (t & 3) * 8;
  const long aBase = (long)(brow + srow) * K;
  const long bBase = (long)(bcol + srow) * K;

  for(int k0 = 0; k0 < K; k0 += 32){
    __syncthreads();
    gload_lds16(A + aBase + k0 + sk,               As + t*8);
    gload_lds16(A + aBase + 64*(long)K + k0 + sk,  As + 2048 + t*8);
    gload_lds16(B + bBase + k0 + sk,               Bs + t*8);
    gload_lds16(B + bBase + 64*(long)K + k0 + sk,  Bs + 2048 + t*8);
    __syncthreads();

    bf16x8 af[4], bfr[4];
    #pragma unroll
    for(int m=0;m<4;++m)
      af[m]  = *(const bf16x8*)((const char*)As + (wrow + m*16 + cc)*64 + gg*16);
    #pragma unroll
    for(int n=0;n<4;++n)
      bfr[n] = *(const bf16x8*)((const char*)Bs + (wcol + n*16 + cc)*64 + gg*16);
    #pragma unroll
    for(int m=0;m<4;++m)
      #pragma unroll
      for(int n=0;n<4;++n)
        acc[m][n] = __builtin_amdgcn_mfma_f32_16x16x32_bf16(af[m], bfr[n], acc[m][n], 0, 0, 0);
  }

  #pragma unroll
  for(int m=0;m<4;++m){
    #pragma unroll
    for(int n=0;n<4;++n){
      const int row0 = brow + wrow + m*16 + gg*4;
      const int col  = bcol + wcol + n*16 + cc;
      const float sc = (QSCALE && col < D_MODEL) ? 0.125f : 1.0f;
      #pragma unroll
      for(int r=0;r<4;++r){
        if constexpr (OUT_BF16 != 0){
          ((unsigned short*)Cv)[(long)(row0 + r)*N + col] = f2bf(acc[m][n][r] * sc);
        } else {
          ((float*)Cv)[(long)(row0 + r)*N + col] = acc[m][n][r];
        }
      }
    }
  }
}

// ---------------- fused causal attention v3 ----------------
// block = (head, 64 q-rows), 4 waves x 16 q-rows. KVBLK=64, double-buffered, 1 barrier/tile.
// Swapped QK^T; P stays in registers via k-permuted PV fragments:
//   pa[hh] slot j = P[q=cc][k-local: j<4 -> 4*gg+j, j>=4 -> 16+4*gg+j]  (lane-local from QK output)
//   bv(vt,hh) matching permutation read as two ds_read_b64 from swizzled V^T.
__global__ __launch_bounds__(256, 4) void attn_fused(const unsigned short* __restrict__ qkv,
                                                     unsigned short* __restrict__ aout){
  __shared__ unsigned short Ks[2][64*64];    // K tile: rows=key (128B), chunk^= (row&7), via gload_lds
  __shared__ unsigned short VTs[2][64*64];   // V^T tile: rows=d (128B=64 k), chunk c'=ko^((d>>1)&7)

  const int t    = threadIdx.x;
  const int lane = t & 63;
  const int w    = t >> 6;
  const int cc   = lane & 15;
  const int gg   = lane >> 4;

  const int bid  = blockIdx.x;
  const int qb   = 63 - (bid >> 4);          // heavy (long-KV) q-blocks first
  const int hd   = bid & 15;
  const int q0w  = qb*64 + w*16;
  const int nkv  = qb + 1;

  // Q fragments (already scaled by 0.125 in gemm epilogue)
  bf16x8 bq0 = *(const bf16x8*)(qkv + (long)(q0w+cc)*E3 + hd*HD +      gg*8);
  bf16x8 bq1 = *(const bf16x8*)(qkv + (long)(q0w+cc)*E3 + hd*HD + 32 + gg*8);

  f32x4 acc[4];
  #pragma unroll
  for(int vt=0;vt<4;++vt) acc[vt] = (f32x4){0.f,0.f,0.f,0.f};
  float rs = 0.f;

  // ---- staging precompute ----
  const long tileStride = 64L * E3;
  // K: 2 passes of gload_lds16; LDS linear dest, pre-swizzled global source
  long kg[2]; int ksd[2];
  #pragma unroll
  for(int p=0;p<2;++p){
    const int s   = p*4096 + t*16;
    const int row = s >> 7;
    const int cp  = ((s>>4)&7) ^ (row&7);
    kg[p]  = (long)row*E3 + D_MODEL + hd*HD + cp*8;
    ksd[p] = s;
  }
  // V: thread covers d = {2dp, 2dp+1}, k = 8ko..8ko+7
  const int dp = t & 31;
  const int ko = t >> 5;
  const long vg = (long)(ko*8)*E3 + 2*D_MODEL + hd*HD + 2*dp;
  const int vchunk = (ko ^ (dp & 7)) * 16;   // byte offset of 16B chunk within V^T row

  #define STAGE_K(kb_, buf_) do{                                                    \
    gload_lds16(qkv + kg[0] + (kb_)*tileStride, (char*)Ks[buf_] + ksd[0]);          \
    gload_lds16(qkv + kg[1] + (kb_)*tileStride, (char*)Ks[buf_] + ksd[1]);          \
  }while(0)

  #define VLOAD(kb_) do{                                                            \
    _Pragma("unroll")                                                               \
    for(int j=0;j<8;++j)                                                            \
      vr[j] = *(const unsigned int*)(qkv + vg + (kb_)*tileStride + (long)j*E3);     \
  }while(0)

  #define VWRITE(buf_) do{                                                          \
    u32x4 lo_, hi_;                                                                 \
    _Pragma("unroll")                                                               \
    for(int j=0;j<4;++j){                                                           \
      lo_[j] = __builtin_amdgcn_perm(vr[2*j+1], vr[2*j], 0x05040100u);              \
      hi_[j] = __builtin_amdgcn_perm(vr[2*j+1], vr[2*j], 0x07060302u);              \
    }                                                                               \
    *(u32x4*)((char*)VTs[buf_] + (2*dp  )*128 + vchunk) = lo_;                      \
    *(u32x4*)((char*)VTs[buf_] + (2*dp+1)*128 + vchunk) = hi_;                      \
  }while(0)

  unsigned int vr[8];
  STAGE_K(0, 0);
  VLOAD(0);
  VWRITE(0);
  __syncthreads();

  for(int kb=0; kb<nkv; ++kb){
    const int cur = kb & 1;
    const bool pf = (kb+1 < nkv);
    if(pf){ STAGE_K(kb+1, cur^1); VLOAD(kb+1); }

    // ---- S^T = K·Q^T, clamp(+-10), mask, exp -> pkf (registers only) ----
    float pkf[4][4];
    #pragma unroll
    for(int kt=0; kt<4; ++kt){
      const bool on = (kb < qb) || (kt <= w);     // wave-uniform
      if(on){
        const char* kro = (const char*)Ks[cur] + (16*kt+cc)*128;
        bf16x8 a0 = *(const bf16x8*)(kro + (((gg  ) ^ (cc&7)) << 4));
        bf16x8 a1 = *(const bf16x8*)(kro + (((gg+4) ^ (cc&7)) << 4));
        f32x4 s = __builtin_amdgcn_mfma_f32_16x16x32_bf16(a0, bq0, (f32x4){0.f,0.f,0.f,0.f}, 0,0,0);
        s = __builtin_amdgcn_mfma_f32_16x16x32_bf16(a1, bq1, s, 0,0,0);
        const bool diag = (kb == qb) && (kt == w); // wave-uniform
        #pragma unroll
        for(int r=0;r<4;++r){
          float sv = fminf(fmaxf(s[r], -10.f), 10.f);
          float p  = __expf(sv);
          if(diag && (4*gg + r > cc)) p = 0.f;
          pkf[kt][r] = p;
          rs += p;
        }
      } else {
        #pragma unroll
        for(int r=0;r<4;++r) pkf[kt][r] = 0.f;
      }
    }

    // pack P fragments (lane-local, permuted k-order)
    bf16x8 pa[2];
    #pragma unroll
    for(int hh=0; hh<2; ++hh)
      pa[hh] = (bf16x8){ (__bf16)pkf[2*hh][0],   (__bf16)pkf[2*hh][1],
                         (__bf16)pkf[2*hh][2],   (__bf16)pkf[2*hh][3],
                         (__bf16)pkf[2*hh+1][0], (__bf16)pkf[2*hh+1][1],
                         (__bf16)pkf[2*hh+1][2], (__bf16)pkf[2*hh+1][3] };

    if(pf) VWRITE(cur^1);

    // ---- O += P · V  (bv in matching permuted k-order) ----
    const int rsw = cc >> 1;                     // ((vt*16+cc)>>1)&7 == cc>>1
    #pragma unroll
    for(int hh=0; hh<2; ++hh){
      const bool hOn = (kb < qb) || (2*hh <= w); // wave-uniform; skip dead half on diagonal
      if(hOn){
        const int ko0 = hh*4 + (gg>>1);
        #pragma unroll
        for(int vt=0; vt<4; ++vt){
          const char* vrow = (const char*)VTs[cur] + (vt*16+cc)*128;
          u32x2 lo = *(const u32x2*)(vrow + (((ko0  ) ^ rsw) << 4) + (gg&1)*8);
          u32x2 hi = *(const u32x2*)(vrow + (((ko0+2) ^ rsw) << 4) + (gg&1)*8);
          bf16x8 bv = __builtin_bit_cast(bf16x8, (u32x4){lo[0], lo[1], hi[0], hi[1]});
          acc[vt] = __builtin_amdgcn_mfma_f32_16x16x32_bf16(pa[hh], bv, acc[vt], 0,0,0);
        }
      }
    }

    __syncthreads();
  }

  // rowsum: lane holds partial for q=cc over its keys; reduce across gg
  rs += __shfl_xor(rs, 16);
  rs += __shfl_xor(rs, 32);

  #pragma unroll
  for(int r=0;r<4;++r){
    const float rsv = __shfl(rs, 4*gg + r);      // lane (cc=4gg+r, gg=0) holds that q's sum
    const float inv = 1.0f / rsv;
    const int row = q0w + 4*gg + r;
    #pragma unroll
    for(int vt=0;vt<4;++vt)
      aout[(long)row*D_MODEL + hd*HD + vt*16 + cc] =
        __builtin_bit_cast(unsigned short, (__bf16)(acc[vt][r] * inv));
  }
  #undef STAGE_K
  #undef VLOAD
  #undef VWRITE
}

extern "C" void kernel_launch(void* const* d_in, const int* in_sizes, int n_in,
                              void* d_out, int out_size, void* d_ws, size_t ws_size,
                              hipStream_t stream){
  (void)in_sizes; (void)n_in; (void)out_size; (void)ws_size;
  const float* x    = (const float*)d_in[0];
  const float* wqkv = (const float*)d_in[1];
  const float* wout = (const float*)d_in[2];
  char* ws = (char*)d_ws;
  unsigned short* xb    = (unsigned short*)(ws);                 //  8 MB
  unsigned short* wqkvb = (unsigned short*)(ws + (8u  << 20));   //  6 MB
  unsigned short* woutb = (unsigned short*)(ws + (14u << 20));   //  2 MB
  unsigned short* qkvb  = (unsigned short*)(ws + (16u << 20));   // 24 MB
  unsigned short* attnb = (unsigned short*)(ws + (40u << 20));   //  8 MB
  float* out = (float*)d_out;

  cvt_f32_bf16<<<(T_SEQ*D_MODEL/4 + 255)/256, 256, 0, stream>>>((const float4*)x,    (u16x4*)xb,    T_SEQ*D_MODEL/4);
  cvt_f32_bf16<<<(E3*D_MODEL/4   + 255)/256, 256, 0, stream>>>((const float4*)wqkv, (u16x4*)wqkvb, E3*D_MODEL/4);
  cvt_f32_bf16<<<(D_MODEL*D_MODEL/4 + 255)/256, 256, 0, stream>>>((const float4*)wout, (u16x4*)woutb, D_MODEL*D_MODEL/4);

  dim3 g1(E3/128, T_SEQ/128);
  gemm_bt<1,1><<<g1, 256, 0, stream>>>(xb, wqkvb, qkvb, T_SEQ, E3, D_MODEL);

  attn_fused<<<dim3(64*NH), 256, 0, stream>>>(qkvb, attnb);

  dim3 g3(D_MODEL/128, T_SEQ/128);
  gemm_bt<0,0><<<g3, 256, 0, stream>>>(attnb, woutb, out, T_SEQ, D_MODEL, D_MODEL);
}